// Round 1
// baseline (3028.391 us; speedup 1.0000x reference)
//
#include <hip/hip_runtime.h>
#include <math.h>

#define D 2048
#define BROWS 1024
#define NEL (D*BROWS)
#define NBLK 1024
#define NTHREADS_TOT (NBLK*256)

// GEMM tile
#define BM 128
#define BN 128
#define BK 16

__device__ __forceinline__ double blk_reduce(double v, double* sm) {
    const int t = threadIdx.x;
    sm[t] = v;
    __syncthreads();
    for (int s = 128; s > 0; s >>= 1) {
        if (t < s) sm[t] += sm[t + s];
        __syncthreads();
    }
    double r = sm[0];
    __syncthreads();
    return r;
}

// ---------------- NT GEMM: out[i][j] = sum_k A[i,k]*B[j,k]  (+ M-build epilogue) ----
// mode 0: out = acc + I - (W + W^T)   (builds M = (W-I)(W^T-I), symmetric by construction)
// mode 1: raw store, split-K via blockIdx.z -> out0/out1
__global__ __launch_bounds__(256) void k_gemm_nt(const float* __restrict__ A,
        const float* __restrict__ Bm, float* __restrict__ out0, float* __restrict__ out1,
        const float* __restrict__ Wadj, int ksz, int mode, const int* __restrict__ frz)
{
    if (frz && *frz) return;
    __shared__ float As[BK][BM + 4];
    __shared__ float Bs[BK][BN + 4];
    const int t  = threadIdx.x;
    const int tx = t & 15, ty = t >> 4;
    const int row0 = blockIdx.y * BM, col0 = blockIdx.x * BN;
    const int k0 = blockIdx.z * ksz;
    float* out = blockIdx.z ? out1 : out0;

    float acc[8][8];
    #pragma unroll
    for (int i = 0; i < 8; ++i)
        #pragma unroll
        for (int j = 0; j < 8; ++j) acc[i][j] = 0.0f;

    for (int kt = 0; kt < ksz; kt += BK) {
        #pragma unroll
        for (int v = 0; v < 2; ++v) {
            const int vid = t + v * 256;           // 0..511
            const int r = vid >> 2, cq = vid & 3;  // row in tile, quad of k
            const float4 ga = *reinterpret_cast<const float4*>(
                &A[(size_t)(row0 + r) * D + (k0 + kt + cq * 4)]);
            As[cq*4+0][r] = ga.x; As[cq*4+1][r] = ga.y;
            As[cq*4+2][r] = ga.z; As[cq*4+3][r] = ga.w;
            const float4 gb = *reinterpret_cast<const float4*>(
                &Bm[(size_t)(col0 + r) * D + (k0 + kt + cq * 4)]);
            Bs[cq*4+0][r] = gb.x; Bs[cq*4+1][r] = gb.y;
            Bs[cq*4+2][r] = gb.z; Bs[cq*4+3][r] = gb.w;
        }
        __syncthreads();
        #pragma unroll
        for (int k = 0; k < BK; ++k) {
            float a[8], b[8];
            *reinterpret_cast<float4*>(&a[0]) = *reinterpret_cast<const float4*>(&As[k][ty*4]);
            *reinterpret_cast<float4*>(&a[4]) = *reinterpret_cast<const float4*>(&As[k][ty*4+64]);
            *reinterpret_cast<float4*>(&b[0]) = *reinterpret_cast<const float4*>(&Bs[k][tx*4]);
            *reinterpret_cast<float4*>(&b[4]) = *reinterpret_cast<const float4*>(&Bs[k][tx*4+64]);
            #pragma unroll
            for (int i = 0; i < 8; ++i)
                #pragma unroll
                for (int j = 0; j < 8; ++j)
                    acc[i][j] += a[i] * b[j];
        }
        __syncthreads();
    }

    #pragma unroll
    for (int i = 0; i < 8; ++i) {
        const int grow = row0 + ((i < 4) ? (ty*4 + i) : (64 + ty*4 + i - 4));
        float vv[8];
        #pragma unroll
        for (int j = 0; j < 8; ++j) vv[j] = acc[i][j];
        if (mode == 0) {
            #pragma unroll
            for (int j = 0; j < 8; ++j) {
                const int gcol = col0 + ((j < 4) ? (tx*4 + j) : (64 + tx*4 + j - 4));
                const float wsum = Wadj[(size_t)grow * D + gcol] + Wadj[(size_t)gcol * D + grow];
                vv[j] += (grow == gcol ? 1.0f : 0.0f) - wsum;
            }
        }
        const float4 o0 = make_float4(vv[0], vv[1], vv[2], vv[3]);
        const float4 o1 = make_float4(vv[4], vv[5], vv[6], vv[7]);
        *reinterpret_cast<float4*>(&out[(size_t)grow * D + col0 + tx*4])      = o0;
        *reinterpret_cast<float4*>(&out[(size_t)grow * D + col0 + 64 + tx*4]) = o1;
    }
}

// ---------------- init: c=z=c0, u=0, partial sums of cos(c0), c0^3 -------------------
__global__ __launch_bounds__(256) void k_init(const float* __restrict__ c0,
        float* __restrict__ c, float* __restrict__ z, float* __restrict__ u,
        double* __restrict__ partials)
{
    __shared__ double sm[256];
    double sc = 0.0, s3 = 0.0;
    const int tid = blockIdx.x * 256 + threadIdx.x;
    for (int i = tid; i < NEL; i += NTHREADS_TOT) {
        const float v = c0[i];
        c[i] = v; z[i] = v; u[i] = 0.0f;
        sc += (double)cosf(v);
        s3 += (double)((v * v) * v);
    }
    const double tc = blk_reduce(sc, sm);
    const double t3 = blk_reduce(s3, sm);
    if (threadIdx.x == 0) { partials[blockIdx.x] = tc; partials[NBLK + blockIdx.x] = t3; }
}

__global__ __launch_bounds__(256) void k_decide0(const double* __restrict__ partials,
        double* __restrict__ scal, int* __restrict__ flag, int* __restrict__ frz)
{
    __shared__ double sm[256];
    const int t = threadIdx.x;
    const double a = partials[t] + partials[t+256] + partials[t+512] + partials[t+768];
    const double b = partials[NBLK+t] + partials[NBLK+t+256] + partials[NBLK+t+512] + partials[NBLK+t+768];
    const double tc = blk_reduce(a, sm);
    const double t3 = blk_reduce(b, sm);
    if (t == 0) {
        const double pas = fabs(tc / (double)NEL);
        const double chi = t3 / (double)NEL;
        scal[0] = pas;      // prev_pas
        scal[1] = -chi;     // prev_score (exp(0)=1)
        scal[2] = chi;      // chi_orig
        *flag = 0;
        *frz = 0;
    }
}

// ---------------- per-iteration elementwise + candidate + reductions ----------------
// P0g holds gemm partial 0 on entry; overwritten with c_next (candidate) in place.
__global__ __launch_bounds__(256) void k_elem(float* __restrict__ P0g,
        const float* __restrict__ P1, const float* __restrict__ c,
        const float* __restrict__ z, const float* __restrict__ u,
        const float* __restrict__ lw, const float* __restrict__ lb,
        double* __restrict__ partials, const int* __restrict__ frz)
{
#pragma clang fp contract(off)
    if (*frz) return;
    __shared__ double sm[256];
    double sc = 0.0, s3 = 0.0;
    const int tid = blockIdx.x * 256 + threadIdx.x;
    for (int i = tid; i < NEL; i += NTHREADS_TOT) {
        const int j = i & (D - 1);
        const float cv = c[i];
        const float g = (P0g[i] + P1[i]) + ((cv - z[i]) + u[i]);   // RHO = 1
        const float lim = 1.0f + 0.5f * fabsf(g);                   // COHESION + MU*|g|
        const float mn = fminf(fabsf(cv), lim);
        const float cy = (cv > 0.0f) ? mn : ((cv < 0.0f) ? -mn : 0.0f);
        const float cnv = (cy * lw[j] + lb[j]) - 0.1f * g;          // STEP = 0.1
        P0g[i] = cnv;
        sc += (double)cosf(cnv);
        s3 += (double)((cnv * cnv) * cnv);
    }
    const double tc = blk_reduce(sc, sm);
    const double t3 = blk_reduce(s3, sm);
    if (threadIdx.x == 0) { partials[blockIdx.x] = tc; partials[NBLK + blockIdx.x] = t3; }
}

__global__ __launch_bounds__(256) void k_decide(const double* __restrict__ partials,
        double* __restrict__ scal, int* __restrict__ flag, int* __restrict__ frz)
{
    __shared__ double sm[256];
    if (*frz) return;
    const int t = threadIdx.x;
    const double a = partials[t] + partials[t+256] + partials[t+512] + partials[t+768];
    const double b = partials[NBLK+t] + partials[NBLK+t+256] + partials[NBLK+t+512] + partials[NBLK+t+768];
    const double tc = blk_reduce(a, sm);
    const double t3 = blk_reduce(b, sm);
    if (t == 0) {
        const double pas = fabs(tc / (double)NEL);
        const double drift = fabs(pas - scal[0]);
        const double chi = t3 / (double)NEL;
        const double score = -chi * exp(-drift / 0.05);             // ZETA = 0.05
        const bool violation = drift > 0.05;
        const bool stable = (score - scal[1]) >= -0.1;              // TAU = 0.1
        const int acc = (!violation && stable) ? 1 : 0;
        *flag = acc;
        if (acc) { scal[0] = pas; scal[1] = score; }
        else     { *frz = 1; }   // pure function of carry: once rejected, rejected forever
    }
}

__global__ __launch_bounds__(256) void k_commit(const float* __restrict__ cn,
        float* __restrict__ c, float* __restrict__ z, float* __restrict__ u,
        const int* __restrict__ flag)
{
#pragma clang fp contract(off)
    if (*flag == 0) return;
    const int tid = blockIdx.x * 256 + threadIdx.x;
    for (int i = tid; i < NEL; i += NTHREADS_TOT) {
        const float cnv = cn[i];
        const float uv = u[i];
        const float zi = cnv + uv;
        float zm = fabsf(zi) - 0.1f;          // LAM/RHO = 0.1
        zm = fmaxf(zm, 0.0f);
        const float zn = (zi > 0.0f) ? zm : ((zi < 0.0f) ? -zm : 0.0f);
        c[i] = cnv;
        z[i] = zn;
        u[i] = uv + (cnv - zn);
    }
}

// ---------------- finalization ------------------------------------------------------
__global__ __launch_bounds__(256) void k_final_rows(const float* __restrict__ c0,
        const float* __restrict__ c, float* __restrict__ outp)
{
#pragma clang fp contract(off)
    __shared__ double sm[256];
    const int row = blockIdx.x;
    const size_t base = (size_t)row * D;
    float tv[8];
    double s1 = 0.0;
    #pragma unroll
    for (int s = 0; s < 8; ++s) {
        const int j = threadIdx.x + s * 256;
        const float s0 = c0[base + j];
        const float delta = c[base + j] - s0;
        const float sym = rintf(delta * 10.0f) / 10.0f;   // round-half-even, /10 like ref
        const float tval = s0 + sym;
        tv[s] = tval;
        s1 += (double)tval;
    }
    const double tot = blk_reduce(s1, sm);
    const float m = (float)(tot / (double)D);
    double s2 = 0.0;
    #pragma unroll
    for (int s = 0; s < 8; ++s) {
        const float dev = tv[s] - m;
        s2 += (double)(dev * dev);
    }
    const double tot2 = blk_reduce(s2, sm);
    const float n = sqrtf((float)tot2);
    const float scale = fminf(1.0f, 10.0f / (n + 1e-8f));  // DP_K = 10
    #pragma unroll
    for (int s = 0; s < 8; ++s) {
        const int j = threadIdx.x + s * 256;
        outp[base + j] = m + (tv[s] - m) * scale;
    }
}

__global__ __launch_bounds__(256) void k_final_glob(const float* __restrict__ c0,
        const float* __restrict__ c, double* __restrict__ partials)
{
    __shared__ double sm[256];
    double s3 = 0.0, sd = 0.0;
    const int tid = blockIdx.x * 256 + threadIdx.x;
    for (int i = tid; i < NEL; i += NTHREADS_TOT) {
        const float v = c[i];
        s3 += (double)((v * v) * v);
        const float d = v - c0[i];
        sd += (double)(d * d);
    }
    const double t3 = blk_reduce(s3, sm);
    const double td = blk_reduce(sd, sm);
    if (threadIdx.x == 0) { partials[blockIdx.x] = t3; partials[NBLK + blockIdx.x] = td; }
}

__global__ __launch_bounds__(256) void k_final_status(const double* __restrict__ partials,
        const double* __restrict__ scal, float* __restrict__ outp)
{
    __shared__ double sm[256];
    const int t = threadIdx.x;
    const double a = partials[t] + partials[t+256] + partials[t+512] + partials[t+768];
    const double b = partials[NBLK+t] + partials[NBLK+t+256] + partials[NBLK+t+512] + partials[NBLK+t+768];
    const double t3 = blk_reduce(a, sm);
    const double td = blk_reduce(b, sm);
    if (t == 0) {
        const double chi_cur = t3 / (double)NEL;
        const double diff = sqrt(td);
        const double chi_orig = scal[2];
        const int s_cur = (chi_cur > 0.0) - (chi_cur < 0.0);
        const int s_org = (chi_orig > 0.0) - (chi_orig < 0.0);
        int status;
        if (s_cur != s_org)   status = 2;
        else if (diff > 5.0)  status = 2;
        else if (diff > 1.0)  status = 1;
        else                  status = 0;
        outp[NEL] = (float)status;
    }
}

extern "C" void kernel_launch(void* const* d_in, const int* in_sizes, int n_in,
                              void* d_out, int out_size, void* d_ws, size_t ws_size,
                              hipStream_t stream)
{
    const float* c0 = (const float*)d_in[0];
    const float* W  = (const float*)d_in[1];
    const float* lw = (const float*)d_in[2];
    const float* lb = (const float*)d_in[3];
    float* outp = (float*)d_out;

    // workspace layout (56 MB + 16 KB)
    float* Mbuf = (float*)d_ws;                 // 2048x2048
    float* c  = Mbuf + (size_t)D * D;
    float* z  = c + NEL;
    float* u  = z + NEL;
    float* P0 = u + NEL;                        // gemm partial 0, then c_next candidate
    float* P1 = P0 + NEL;                       // gemm partial 1
    double* partials = (double*)(P1 + NEL);     // 2*NBLK doubles
    double* scal = partials + 2 * NBLK;         // [prev_pas, prev_score, chi_orig, pad]
    int* flag = (int*)(scal + 4);
    int* frz  = flag + 1;

    // M = (W - I)(W^T - I) = W W^T - W - W^T + I  (symmetric, built once)
    k_gemm_nt<<<dim3(D / BN, D / BM, 1), 256, 0, stream>>>(W, W, Mbuf, Mbuf, W, D, 0, nullptr);
    k_init<<<NBLK, 256, 0, stream>>>(c0, c, z, u, partials);
    k_decide0<<<1, 256, 0, stream>>>(partials, scal, flag, frz);

    for (int it = 0; it < 20; ++it) {
        // g_lin = c @ M  (M symmetric -> NT gemm on M rows), split-K=2 -> 256 blocks
        k_gemm_nt<<<dim3(D / BN, BROWS / BM, 2), 256, 0, stream>>>(c, Mbuf, P0, P1, nullptr, D / 2, 1, frz);
        k_elem<<<NBLK, 256, 0, stream>>>(P0, P1, c, z, u, lw, lb, partials, frz);
        k_decide<<<1, 256, 0, stream>>>(partials, scal, flag, frz);
        k_commit<<<NBLK, 256, 0, stream>>>(P0, c, z, u, flag);
    }

    k_final_rows<<<BROWS, 256, 0, stream>>>(c0, c, outp);
    k_final_glob<<<NBLK, 256, 0, stream>>>(c0, c, partials);
    k_final_status<<<1, 256, 0, stream>>>(partials, scal, outp);
}

// Round 3
// 2910.813 us; speedup vs baseline: 1.0404x; 1.0404x over previous
//
#include <hip/hip_runtime.h>
#include <math.h>

#define D 2048
#define BROWS 1024
#define NEL (D*BROWS)
#define NBLK 1024
#define NTHREADS_TOT (NBLK*256)

// GEMM tile: 64 (A rows) x 128 (out cols), BK=16, 256 threads, acc 4x8
#define GM 64
#define GN 128
#define GK 16

__device__ __forceinline__ double blk_reduce(double v, double* sm) {
    const int t = threadIdx.x;
    sm[t] = v;
    __syncthreads();
    for (int s = 128; s > 0; s >>= 1) {
        if (t < s) sm[t] += sm[t + s];
        __syncthreads();
    }
    double r = sm[0];
    __syncthreads();
    return r;
}

// NT GEMM: out[i][j] = sum_k A[i,k]*B[j,k]
// mode 0: full-K, out = acc + I - (W + W^T) fused epilogue (builds M, R1-exact association)
// mode 1: raw store, split-K via blockIdx.z -> P0/P1 (same per-element k-order as R1)
__global__ __launch_bounds__(256) void k_gemm(const float* __restrict__ A,
        const float* __restrict__ B, float* __restrict__ P0, float* __restrict__ P1,
        const float* __restrict__ Wadj, int ksz, int mode, const int* __restrict__ frz)
{
    if (frz && *frz) return;
    __shared__ float As[GK][GM + 4];
    __shared__ float Bs[GK][GN + 4];
    const int t  = threadIdx.x;
    const int tx = t & 15, ty = t >> 4;
    const int row0 = blockIdx.y * GM, col0 = blockIdx.x * GN;
    const int k0 = blockIdx.z * ksz;
    float* __restrict__ out = blockIdx.z ? P1 : P0;

    float acc[4][8];
    #pragma unroll
    for (int i = 0; i < 4; ++i)
        #pragma unroll
        for (int j = 0; j < 8; ++j) acc[i][j] = 0.0f;

    const int ra = t >> 2, ca = t & 3;
    for (int kt = 0; kt < ksz; kt += GK) {
        const int kb = k0 + kt;
        const float4 ga = *reinterpret_cast<const float4*>(
            &A[(size_t)(row0 + ra) * D + kb + ca * 4]);
        As[ca*4+0][ra] = ga.x; As[ca*4+1][ra] = ga.y;
        As[ca*4+2][ra] = ga.z; As[ca*4+3][ra] = ga.w;
        #pragma unroll
        for (int v = 0; v < 2; ++v) {
            const int vid = t + v * 256;
            const int rb = vid >> 2, cb = vid & 3;
            const float4 gb = *reinterpret_cast<const float4*>(
                &B[(size_t)(col0 + rb) * D + kb + cb * 4]);
            Bs[cb*4+0][rb] = gb.x; Bs[cb*4+1][rb] = gb.y;
            Bs[cb*4+2][rb] = gb.z; Bs[cb*4+3][rb] = gb.w;
        }
        __syncthreads();
        #pragma unroll
        for (int k = 0; k < GK; ++k) {
            float a[4], b[8];
            *reinterpret_cast<float4*>(&a[0]) = *reinterpret_cast<const float4*>(&As[k][ty*4]);
            *reinterpret_cast<float4*>(&b[0]) = *reinterpret_cast<const float4*>(&Bs[k][tx*4]);
            *reinterpret_cast<float4*>(&b[4]) = *reinterpret_cast<const float4*>(&Bs[k][64 + tx*4]);
            #pragma unroll
            for (int i = 0; i < 4; ++i)
                #pragma unroll
                for (int j = 0; j < 8; ++j)
                    acc[i][j] += a[i] * b[j];
        }
        __syncthreads();
    }
    #pragma unroll
    for (int i = 0; i < 4; ++i) {
        const int grow = row0 + ty*4 + i;
        float vv[8];
        #pragma unroll
        for (int j = 0; j < 8; ++j) vv[j] = acc[i][j];
        if (mode == 0) {
            #pragma unroll
            for (int j = 0; j < 8; ++j) {
                const int gcol = col0 + ((j < 4) ? (tx*4 + j) : (64 + tx*4 + j - 4));
                const float wsum = Wadj[(size_t)grow * D + gcol] + Wadj[(size_t)gcol * D + grow];
                vv[j] += (grow == gcol ? 1.0f : 0.0f) - wsum;
            }
        }
        float* orow = &out[(size_t)grow * D + col0];
        *reinterpret_cast<float4*>(&orow[tx*4]) =
            make_float4(vv[0], vv[1], vv[2], vv[3]);
        *reinterpret_cast<float4*>(&orow[64 + tx*4]) =
            make_float4(vv[4], vv[5], vv[6], vv[7]);
    }
}

__global__ __launch_bounds__(256) void k_init(const float* __restrict__ c0,
        float* __restrict__ c, float* __restrict__ z, float* __restrict__ u,
        double* __restrict__ partials)
{
    __shared__ double sm[256];
    double sc = 0.0, s3 = 0.0;
    const int tid = blockIdx.x * 256 + threadIdx.x;
    for (int i = tid; i < NEL; i += NTHREADS_TOT) {
        const float v = c0[i];
        c[i] = v; z[i] = v; u[i] = 0.0f;
        sc += (double)cosf(v);
        s3 += (double)((v * v) * v);
    }
    const double tc = blk_reduce(sc, sm);
    const double t3 = blk_reduce(s3, sm);
    if (threadIdx.x == 0) { partials[blockIdx.x] = tc; partials[NBLK + blockIdx.x] = t3; }
}

__global__ __launch_bounds__(256) void k_decide0(const double* __restrict__ partials,
        double* __restrict__ scal, int* __restrict__ flag, int* __restrict__ frz,
        int* __restrict__ sel)
{
    __shared__ double sm[256];
    const int t = threadIdx.x;
    const double a = partials[t] + partials[t+256] + partials[t+512] + partials[t+768];
    const double b = partials[NBLK+t] + partials[NBLK+t+256] + partials[NBLK+t+512] + partials[NBLK+t+768];
    const double tc = blk_reduce(a, sm);
    const double t3 = blk_reduce(b, sm);
    if (t == 0) {
        const double pas = fabs(tc / (double)NEL);
        const double chi = t3 / (double)NEL;
        scal[0] = pas; scal[1] = -chi; scal[2] = chi;
        *flag = 0; *frz = 0; *sel = 0;
    }
}

// fused candidate + speculative z/u in-place commit + reductions (ping-pong c)
__global__ __launch_bounds__(256) void k_elem_pp(const float* __restrict__ P0,
        const float* __restrict__ P1, const float* __restrict__ cc,
        float* __restrict__ cn, float* __restrict__ z, float* __restrict__ u,
        const float* __restrict__ lw, const float* __restrict__ lb,
        double* __restrict__ partials, const int* __restrict__ frz)
{
#pragma clang fp contract(off)
    if (*frz) return;
    __shared__ double sm[256];
    double sc = 0.0, s3 = 0.0;
    const int tid = blockIdx.x * 256 + threadIdx.x;
    for (int i = tid; i < NEL; i += NTHREADS_TOT) {
        const int j = i & (D - 1);
        const float cv = cc[i];
        const float zv = z[i];
        const float uv = u[i];
        const float g = (P0[i] + P1[i]) + ((cv - zv) + uv);        // RHO = 1
        const float lim = 1.0f + 0.5f * fabsf(g);                  // COHESION + MU*|g|
        const float mn = fminf(fabsf(cv), lim);
        const float cy = (cv > 0.0f) ? mn : ((cv < 0.0f) ? -mn : 0.0f);
        const float cnv = (cy * lw[j] + lb[j]) - 0.1f * g;         // STEP = 0.1
        cn[i] = cnv;
        const float zi = cnv + uv;
        float zm = fabsf(zi) - 0.1f;                               // LAM/RHO
        zm = fmaxf(zm, 0.0f);
        const float zn = (zi > 0.0f) ? zm : ((zi < 0.0f) ? -zm : 0.0f);
        z[i] = zn;
        u[i] = uv + (cnv - zn);
        sc += (double)cosf(cnv);
        s3 += (double)((cnv * cnv) * cnv);
    }
    const double tc = blk_reduce(sc, sm);
    const double t3 = blk_reduce(s3, sm);
    if (threadIdx.x == 0) { partials[blockIdx.x] = tc; partials[NBLK + blockIdx.x] = t3; }
}

// legacy (no ping-pong): candidate into P0, commit separately
__global__ __launch_bounds__(256) void k_elem(float* __restrict__ P0,
        const float* __restrict__ P1, const float* __restrict__ c,
        const float* __restrict__ z, const float* __restrict__ u,
        const float* __restrict__ lw, const float* __restrict__ lb,
        double* __restrict__ partials, const int* __restrict__ frz)
{
#pragma clang fp contract(off)
    if (*frz) return;
    __shared__ double sm[256];
    double sc = 0.0, s3 = 0.0;
    const int tid = blockIdx.x * 256 + threadIdx.x;
    for (int i = tid; i < NEL; i += NTHREADS_TOT) {
        const int j = i & (D - 1);
        const float cv = c[i];
        const float g = (P0[i] + P1[i]) + ((cv - z[i]) + u[i]);
        const float lim = 1.0f + 0.5f * fabsf(g);
        const float mn = fminf(fabsf(cv), lim);
        const float cy = (cv > 0.0f) ? mn : ((cv < 0.0f) ? -mn : 0.0f);
        const float cnv = (cy * lw[j] + lb[j]) - 0.1f * g;
        P0[i] = cnv;
        sc += (double)cosf(cnv);
        s3 += (double)((cnv * cnv) * cnv);
    }
    const double tc = blk_reduce(sc, sm);
    const double t3 = blk_reduce(s3, sm);
    if (threadIdx.x == 0) { partials[blockIdx.x] = tc; partials[NBLK + blockIdx.x] = t3; }
}

__global__ __launch_bounds__(256) void k_decide(const double* __restrict__ partials,
        double* __restrict__ scal, int* __restrict__ flag, int* __restrict__ frz,
        int* __restrict__ sel, int next_sel)
{
    __shared__ double sm[256];
    if (*frz) return;
    const int t = threadIdx.x;
    const double a = partials[t] + partials[t+256] + partials[t+512] + partials[t+768];
    const double b = partials[NBLK+t] + partials[NBLK+t+256] + partials[NBLK+t+512] + partials[NBLK+t+768];
    const double tc = blk_reduce(a, sm);
    const double t3 = blk_reduce(b, sm);
    if (t == 0) {
        const double pas = fabs(tc / (double)NEL);
        const double drift = fabs(pas - scal[0]);
        const double chi = t3 / (double)NEL;
        const double score = -chi * exp(-drift / 0.05);            // ZETA
        const bool violation = drift > 0.05;
        const bool stable = (score - scal[1]) >= -0.1;             // TAU
        const int acc = (!violation && stable) ? 1 : 0;
        *flag = acc;
        if (acc) { scal[0] = pas; scal[1] = score; *sel = next_sel; }
        else     { *frz = 1; }   // carry is pure: once rejected, rejected forever
    }
}

__global__ __launch_bounds__(256) void k_commit(const float* __restrict__ cn,
        float* __restrict__ c, float* __restrict__ z, float* __restrict__ u,
        const int* __restrict__ flag)
{
#pragma clang fp contract(off)
    if (*flag == 0) return;
    const int tid = blockIdx.x * 256 + threadIdx.x;
    for (int i = tid; i < NEL; i += NTHREADS_TOT) {
        const float cnv = cn[i];
        const float uv = u[i];
        const float zi = cnv + uv;
        float zm = fabsf(zi) - 0.1f;
        zm = fmaxf(zm, 0.0f);
        const float zn = (zi > 0.0f) ? zm : ((zi < 0.0f) ? -zm : 0.0f);
        c[i] = cnv;
        z[i] = zn;
        u[i] = uv + (cnv - zn);
    }
}

__global__ __launch_bounds__(256) void k_final_rows(const float* __restrict__ c0,
        const float* __restrict__ cA, const float* __restrict__ cB,
        const int* __restrict__ sel, float* __restrict__ outp)
{
#pragma clang fp contract(off)
    __shared__ double sm[256];
    const float* __restrict__ c = (*sel) ? cB : cA;
    const int row = blockIdx.x;
    const size_t base = (size_t)row * D;
    float tv[8];
    double s1 = 0.0;
    #pragma unroll
    for (int s = 0; s < 8; ++s) {
        const int j = threadIdx.x + s * 256;
        const float s0 = c0[base + j];
        const float delta = c[base + j] - s0;
        const float sym = rintf(delta * 10.0f) / 10.0f;
        const float tval = s0 + sym;
        tv[s] = tval;
        s1 += (double)tval;
    }
    const double tot = blk_reduce(s1, sm);
    const float m = (float)(tot / (double)D);
    double s2 = 0.0;
    #pragma unroll
    for (int s = 0; s < 8; ++s) {
        const float dev = tv[s] - m;
        s2 += (double)(dev * dev);
    }
    const double tot2 = blk_reduce(s2, sm);
    const float n = sqrtf((float)tot2);
    const float scale = fminf(1.0f, 10.0f / (n + 1e-8f));
    #pragma unroll
    for (int s = 0; s < 8; ++s) {
        const int j = threadIdx.x + s * 256;
        outp[base + j] = m + (tv[s] - m) * scale;
    }
}

__global__ __launch_bounds__(256) void k_final_glob(const float* __restrict__ c0,
        const float* __restrict__ cA, const float* __restrict__ cB,
        const int* __restrict__ sel, double* __restrict__ partials)
{
    __shared__ double sm[256];
    const float* __restrict__ c = (*sel) ? cB : cA;
    double s3 = 0.0, sd = 0.0;
    const int tid = blockIdx.x * 256 + threadIdx.x;
    for (int i = tid; i < NEL; i += NTHREADS_TOT) {
        const float v = c[i];
        s3 += (double)((v * v) * v);
        const float d = v - c0[i];
        sd += (double)(d * d);
    }
    const double t3 = blk_reduce(s3, sm);
    const double td = blk_reduce(sd, sm);
    if (threadIdx.x == 0) { partials[blockIdx.x] = t3; partials[NBLK + blockIdx.x] = td; }
}

__global__ __launch_bounds__(256) void k_final_status(const double* __restrict__ partials,
        const double* __restrict__ scal, float* __restrict__ outp)
{
    __shared__ double sm[256];
    const int t = threadIdx.x;
    const double a = partials[t] + partials[t+256] + partials[t+512] + partials[t+768];
    const double b = partials[NBLK+t] + partials[NBLK+t+256] + partials[NBLK+t+512] + partials[NBLK+t+768];
    const double t3 = blk_reduce(a, sm);
    const double td = blk_reduce(b, sm);
    if (t == 0) {
        const double chi_cur = t3 / (double)NEL;
        const double diff = sqrt(td);
        const double chi_orig = scal[2];
        const int s_cur = (chi_cur > 0.0) - (chi_cur < 0.0);
        const int s_org = (chi_orig > 0.0) - (chi_orig < 0.0);
        int status;
        if (s_cur != s_org)   status = 2;
        else if (diff > 5.0)  status = 2;
        else if (diff > 1.0)  status = 1;
        else                  status = 0;
        outp[NEL] = (float)status;
    }
}

extern "C" void kernel_launch(void* const* d_in, const int* in_sizes, int n_in,
                              void* d_out, int out_size, void* d_ws, size_t ws_size,
                              hipStream_t stream)
{
    const float* c0 = (const float*)d_in[0];
    const float* W  = (const float*)d_in[1];
    const float* lw = (const float*)d_in[2];
    const float* lb = (const float*)d_in[3];
    float* outp = (float*)d_out;

    const size_t M4 = (size_t)D * D;    // 4M floats
    const size_t N4 = (size_t)NEL;      // 2M floats
    float* Mb = (float*)d_ws;
    float* region = Mb + M4;

    const size_t tail_bytes = (2 * NBLK + 8) * sizeof(double) + 4 * sizeof(int);
    const bool pp = ws_size >= (M4 + 6 * N4) * sizeof(float) + tail_bytes;

    float *cA, *cB, *z, *u, *P0, *P1;
    if (pp) { cA = region; cB = cA + N4; z = cB + N4; u = z + N4; P0 = u + N4; P1 = P0 + N4; }
    else    { cA = region; cB = cA;      z = cA + N4; u = z + N4; P0 = u + N4; P1 = P0 + N4; }
    double* partials = (double*)(P1 + N4);
    double* scal = partials + 2 * NBLK;
    int* flag = (int*)(scal + 8);
    int* frz  = flag + 1;
    int* sel  = frz + 1;

    // M = (W-I)(W^T-I) = W W^T + I - W - W^T, full-K fused epilogue (R1-exact bits)
    k_gemm<<<dim3(D / GN, D / GM, 1), 256, 0, stream>>>(W, W, Mb, Mb, W, D, 0, nullptr);
    k_init<<<NBLK, 256, 0, stream>>>(c0, cA, z, u, partials);
    k_decide0<<<1, 256, 0, stream>>>(partials, scal, flag, frz, sel);

    for (int t = 0; t < 20; ++t) {
        const float* ccur = (pp && (t & 1)) ? cB : cA;
        float* cnxt = (pp && !(t & 1)) ? cB : cA;
        k_gemm<<<dim3(D / GN, BROWS / GM, 2), 256, 0, stream>>>(ccur, Mb, P0, P1, nullptr, D / 2, 1, frz);
        if (pp) {
            k_elem_pp<<<NBLK, 256, 0, stream>>>(P0, P1, ccur, cnxt, z, u, lw, lb, partials, frz);
            k_decide<<<1, 256, 0, stream>>>(partials, scal, flag, frz, sel, (t + 1) & 1);
        } else {
            k_elem<<<NBLK, 256, 0, stream>>>(P0, P1, cA, z, u, lw, lb, partials, frz);
            k_decide<<<1, 256, 0, stream>>>(partials, scal, flag, frz, sel, 0);
            k_commit<<<NBLK, 256, 0, stream>>>(P0, cA, z, u, flag);
        }
    }

    k_final_rows<<<BROWS, 256, 0, stream>>>(c0, cA, cB, sel, outp);
    k_final_glob<<<NBLK, 256, 0, stream>>>(c0, cA, cB, sel, partials);
    k_final_status<<<1, 256, 0, stream>>>(partials, scal, outp);
}